// Round 6
// baseline (74.037 us; speedup 1.0000x reference)
//
#include <hip/hip_runtime.h>

#define VOCAB 100000
#define D     300
#define B     256
#define L     1000
#define H     512
#define C     5

#define D4    75           // float4 per embedding row
#define NG    8            // row groups per gather block
#define GL    80           // lanes per group (75 active)
#define RPG   125          // rows per group
#define NT    640          // gather block threads

// ws layout (floats)
#define WS_AVG 0                       // B*D   = 76800
#define WS_H1  (B * D)                 // B*H   = 131072
#define WS_H2  (WS_H1 + B * H)         // total ~1.4 MB

// ---------------------------------------------------------------------------
// K1: gather + mean. 256 blocks x 640 threads. waves_per_eu(2,3) lifts the
// scheduler's occupancy target so it keeps register batches of loads in
// flight (R5: VGPR=40 -> serialized loads -> 1.9 TB/s).
// Ping-pong double-buffered batches of 5 rows: ~10 loads in flight/lane.
// ---------------------------------------------------------------------------
__global__ __launch_bounds__(NT)
__attribute__((amdgpu_waves_per_eu(2, 3)))
void gather_mean_kernel(const float* __restrict__ emb,
                        const int* __restrict__ docs,
                        const int* __restrict__ dlen,
                        float* __restrict__ avg) {
  const int b = blockIdx.x;
  const int t = threadIdx.x;

  __shared__ int    sidx[L];
  __shared__ float4 sred[NG][D4];

  if (t < L / 4)
    reinterpret_cast<int4*>(sidx)[t] =
        reinterpret_cast<const int4*>(docs + (size_t)b * L)[t];
  __syncthreads();

  const int g = t / GL;
  const int lane = t - g * GL;
  const float4* ep4 = reinterpret_cast<const float4*>(emb);

  if (lane < D4) {
    const int base = g * RPG;
    float ax = 0.f, ay = 0.f, az = 0.f, aw = 0.f;
    float4 va[5], vb[5];

    auto loadb = [&](float4* v, int off) {
#pragma unroll
      for (int j = 0; j < 5; ++j) {
        const int r = sidx[base + off + j] * D4 + lane;  // float4 index
        v[j] = ep4[r];
      }
    };
    auto accb = [&](const float4* v) {
#pragma unroll
      for (int j = 0; j < 5; ++j) {
        ax += v[j].x; ay += v[j].y; az += v[j].z; aw += v[j].w;
      }
    };

    loadb(va, 0);
#pragma unroll 1
    for (int p = 0; p < 12; ++p) {
      loadb(vb, 10 * p + 5);
      __builtin_amdgcn_sched_barrier(0);
      accb(va);
      loadb(va, 10 * p + 10);
      __builtin_amdgcn_sched_barrier(0);
      accb(vb);
    }
    accb(va);  // batch at offset 120
    sred[g][lane] = make_float4(ax, ay, az, aw);
  }
  __syncthreads();

  if (t < D4) {
    float ax = 0.f, ay = 0.f, az = 0.f, aw = 0.f;
#pragma unroll
    for (int gg = 0; gg < NG; ++gg) {
      const float4 v = sred[gg][t];
      ax += v.x; ay += v.y; az += v.z; aw += v.w;
    }
    const float inv = 1.f / (float)dlen[b];
    reinterpret_cast<float4*>(avg + (size_t)b * D)[t] =
        make_float4(ax * inv, ay * inv, az * inv, aw * inv);
  }
}

// ---------------------------------------------------------------------------
// K2: h1 = relu(avg @ W1 + b1). grid (16 doc-tiles, 16 col-tiles); block 512
// = 4 k-slices x 16 docs x 8 col-groups(4 cols). Weights/CU = 38 KB.
// ---------------------------------------------------------------------------
__global__ __launch_bounds__(512)
__attribute__((amdgpu_waves_per_eu(2, 4)))
void l1_kernel(const float* __restrict__ avg, const float* __restrict__ W1,
               const float* __restrict__ b1, float* __restrict__ h1) {
  const int dq = blockIdx.x;        // doc tile (16 docs)
  const int cq = blockIdx.y;        // col tile (32 cols)
  const int t = threadIdx.x;
  const int cg = t & 7;             // col group: 4 cols
  const int doc = (t >> 3) & 15;
  const int ks = t >> 7;            // k-slice 0..3 (75 each)

  __shared__ __align__(16) float s_avg[16][D];
  __shared__ __align__(16) float s_comb[4][16][32];

  for (int i = t; i < 16 * D4; i += 512) {
    const int dd = i / D4, c4 = i - dd * D4;
    reinterpret_cast<float4*>(&s_avg[dd][0])[c4] =
        reinterpret_cast<const float4*>(avg + (size_t)(dq * 16 + dd) * D)[c4];
  }
  __syncthreads();

  const int c0 = cq * 32 + cg * 4;
  const int k0 = ks * 75;
  float ax = 0.f, ay = 0.f, az = 0.f, aw = 0.f;
#pragma unroll 1
  for (int i0 = 0; i0 < 75; i0 += 15) {
    float4 w[15];
    float x[15];
#pragma unroll
    for (int j = 0; j < 15; ++j)
      w[j] = *reinterpret_cast<const float4*>(&W1[(size_t)(k0 + i0 + j) * H + c0]);
#pragma unroll
    for (int j = 0; j < 15; ++j) x[j] = s_avg[doc][k0 + i0 + j];
    __builtin_amdgcn_sched_barrier(0);
#pragma unroll
    for (int j = 0; j < 15; ++j) {
      ax += x[j] * w[j].x; ay += x[j] * w[j].y;
      az += x[j] * w[j].z; aw += x[j] * w[j].w;
    }
  }
  *reinterpret_cast<float4*>(&s_comb[ks][doc][cg * 4]) =
      make_float4(ax, ay, az, aw);
  __syncthreads();

  {
    const int dd = t >> 5, col = t & 31;
    const float v = s_comb[0][dd][col] + s_comb[1][dd][col] +
                    s_comb[2][dd][col] + s_comb[3][dd][col] +
                    b1[cq * 32 + col];
    h1[(size_t)(dq * 16 + dd) * H + cq * 32 + col] = fmaxf(v, 0.f);
  }
}

// ---------------------------------------------------------------------------
// K3: h2 = relu(h1 @ W2 + b2). Same shape, K=512 (k-slice 128). LDS input
// padded [16][516] to kill the stride-512 bank conflict on x reads.
// ---------------------------------------------------------------------------
__global__ __launch_bounds__(512)
__attribute__((amdgpu_waves_per_eu(2, 4)))
void l2_kernel(const float* __restrict__ h1, const float* __restrict__ W2,
               const float* __restrict__ b2, float* __restrict__ h2) {
  const int dq = blockIdx.x;
  const int cq = blockIdx.y;
  const int t = threadIdx.x;
  const int cg = t & 7;
  const int doc = (t >> 3) & 15;
  const int ks = t >> 7;

  __shared__ __align__(16) float s_h[16][H + 4];
  __shared__ __align__(16) float s_comb[4][16][32];

  for (int i = t; i < 16 * (H / 4); i += 512) {
    const int dd = i >> 7, c4 = i & 127;
    reinterpret_cast<float4*>(&s_h[dd][0])[c4] =
        reinterpret_cast<const float4*>(h1 + (size_t)(dq * 16 + dd) * H)[c4];
  }
  __syncthreads();

  const int c0 = cq * 32 + cg * 4;
  const int k0 = ks * 128;
  float ax = 0.f, ay = 0.f, az = 0.f, aw = 0.f;
#pragma unroll 1
  for (int i0 = 0; i0 < 128; i0 += 16) {
    float4 w[16];
    float x[16];
#pragma unroll
    for (int j = 0; j < 16; ++j)
      w[j] = *reinterpret_cast<const float4*>(&W2[(size_t)(k0 + i0 + j) * H + c0]);
#pragma unroll
    for (int j = 0; j < 16; ++j) x[j] = s_h[doc][k0 + i0 + j];
    __builtin_amdgcn_sched_barrier(0);
#pragma unroll
    for (int j = 0; j < 16; ++j) {
      ax += x[j] * w[j].x; ay += x[j] * w[j].y;
      az += x[j] * w[j].z; aw += x[j] * w[j].w;
    }
  }
  *reinterpret_cast<float4*>(&s_comb[ks][doc][cg * 4]) =
      make_float4(ax, ay, az, aw);
  __syncthreads();

  {
    const int dd = t >> 5, col = t & 31;
    const float v = s_comb[0][dd][col] + s_comb[1][dd][col] +
                    s_comb[2][dd][col] + s_comb[3][dd][col] +
                    b2[cq * 32 + col];
    h2[(size_t)(dq * 16 + dd) * H + cq * 32 + col] = fmaxf(v, 0.f);
  }
}

// ---------------------------------------------------------------------------
// K4: out = h2 @ W3 + b3. 256 blocks x 64 threads (W3 is 10 KB, L1/L2-hot).
// ---------------------------------------------------------------------------
__global__ __launch_bounds__(64) void head_kernel(
    const float* __restrict__ h2, const float* __restrict__ W3,
    const float* __restrict__ b3, float* __restrict__ out) {
  const int b = blockIdx.x;
  const int l = threadIdx.x;
  float acc[C] = {0.f, 0.f, 0.f, 0.f, 0.f};
#pragma unroll
  for (int i = 0; i < H / 64; ++i) {
    const int h = i * 64 + l;
    const float v = h2[(size_t)b * H + h];
#pragma unroll
    for (int c = 0; c < C; ++c) acc[c] += v * W3[h * C + c];
  }
#pragma unroll
  for (int c = 0; c < C; ++c) {
    float a = acc[c];
#pragma unroll
    for (int off = 32; off > 0; off >>= 1) a += __shfl_down(a, off);
    if (l == 0) out[b * C + c] = a + b3[c];
  }
}

// ---------------------------------------------------------------------------
extern "C" void kernel_launch(void* const* d_in, const int* in_sizes, int n_in,
                              void* d_out, int out_size, void* d_ws,
                              size_t ws_size, hipStream_t stream) {
  const float* emb  = (const float*)d_in[0];
  const float* W1   = (const float*)d_in[1];
  const float* b1   = (const float*)d_in[2];
  const float* W2   = (const float*)d_in[3];
  const float* b2   = (const float*)d_in[4];
  const float* W3   = (const float*)d_in[5];
  const float* b3   = (const float*)d_in[6];
  const int*   docs = (const int*)d_in[7];
  const int*   dlen = (const int*)d_in[8];
  float* out = (float*)d_out;

  float* ws = (float*)d_ws;
  float* avg = ws + WS_AVG;
  float* h1  = ws + WS_H1;
  float* h2  = ws + WS_H2;

  gather_mean_kernel<<<B, NT, 0, stream>>>(emb, docs, dlen, avg);
  dim3 gl(16, 16);
  l1_kernel<<<gl, 512, 0, stream>>>(avg, W1, b1, h1);
  l2_kernel<<<gl, 512, 0, stream>>>(h1, W2, b2, h2);
  head_kernel<<<B, 64, 0, stream>>>(h2, W3, b3, out);
}